// Round 3
// baseline (30.371 us; speedup 1.0000x reference)
//
#include <hip/hip_runtime.h>
#include <math.h>

#define L_OBS   512
#define NSEG    8192
#define NB      8
#define EPS_PAR 1e-4f
#define ANG_STEP 0.012271846644580566f  // FOV / L_OBS
#define SC      16
#define SEGS    (NSEG / SC)             // 512 segments per chunk

// ws layout (scalar path): recs[NB*NSEG*8] floats (2MB), then partial[SC][NB*L_OBS] (256KB)
#define REC_FLOATS   8
#define RECS_FLOATS  (NB * NSEG * REC_FLOATS)
#define PART_FLOATS  (SC * NB * L_OBS)

// Precompute per-(b,seg): {sx, sy, xd, yd, na, pad3} — makes the raycast loop's
// per-segment data wave-uniform-loadable with zero in-loop uniform float math.
__global__ __launch_bounds__(256) void prep_kernel(const float4* __restrict__ seg,
                                                   const float* __restrict__ pose,
                                                   float* __restrict__ recs) {
    int t = blockIdx.x * blockDim.x + threadIdx.x;   // 65536 = NB*NSEG
    int b = t >> 13, s = t & (NSEG - 1);
    float4 v = seg[s];
    float x1 = pose[b * 3 + 0], y1 = pose[b * 3 + 1];
    float sx = v.z - v.x, sy = v.w - v.y;
    float xd = x1 - v.x,  yd = y1 - v.y;
    float na = sx * yd - sy * xd;
    float4* r = (float4*)(recs + (size_t)t * REC_FLOATS);
    r[0] = make_float4(sx, sy, xd, yd);
    r[1] = make_float4(na, 0.0f, 0.0f, 0.0f);
}

// Block = (b, beamgroup of 64, segchunk of 512). lane = beam; wave = 128-seg subchunk.
// Segment records are wave-uniform -> scalar (SMEM) loads, LDS pipe stays idle.
__global__ __launch_bounds__(256) void raycast_scalar_kernel(
    const float* __restrict__ recs, const float* __restrict__ pose,
    float* __restrict__ part) {
    __shared__ float s_red[4][64];

    const int gid = blockIdx.x;
    const int sc = gid & (SC - 1);
    const int bg = (gid >> 4) & 7;
    const int b  = gid >> 7;

    const int tid  = threadIdx.x;
    const int lane = tid & 63;
    const int w    = __builtin_amdgcn_readfirstlane(tid >> 6);

    const float th = pose[b * 3 + 2];
    const int beam = bg * 64 + lane;
    const float ang = (float)beam * ANG_STEP + th;
    const float rx = cosf(ang);
    const float ry = sinf(ang);
    const float INF = __builtin_inff();

    // base record index for this wave's 128 segments
    const float* __restrict__ rp =
        recs + (size_t)((b << 13) + (sc << 9) + (w << 7)) * REC_FLOATS;

    float umin = INF;
    #pragma unroll 8
    for (int i = 0; i < 128; ++i) {
        float4 A  = *(const float4*)(rp + i * REC_FLOATS);   // sx, sy, xd, yd
        float  na = rp[i * REC_FLOATS + 4];
        float rxs = A.y * rx - A.x * ry;
        float nb  = A.w * rx - A.z * ry;
        float r   = __builtin_amdgcn_rcpf(rxs);
        float ua  = na * r;
        float ub  = nb * r;
        bool ok = (fabsf(rxs) >= EPS_PAR) & (ub >= 0.0f) & (ub <= 1.0f) & (ua >= 0.0f);
        umin = fminf(umin, ok ? ua : INF);
    }

    s_red[w][lane] = umin;
    __syncthreads();
    if (w == 0) {
        float m = fminf(fminf(s_red[0][lane], s_red[1][lane]),
                        fminf(s_red[2][lane], s_red[3][lane]));
        part[sc * (NB * L_OBS) + b * L_OBS + beam] = m;
    }
}

__global__ void finalize_part_kernel(const float4* __restrict__ seg,
                                     const float* __restrict__ pose,
                                     const float* __restrict__ part,
                                     float* __restrict__ out) {
    int t = blockIdx.x * blockDim.x + threadIdx.x;
    if (t >= NB * L_OBS) return;
    const int b    = t >> 9;
    const int beam = t & (L_OBS - 1);
    const float x1 = pose[b * 3 + 0];
    const float y1 = pose[b * 3 + 1];
    const float th = pose[b * 3 + 2];
    const float ang = (float)beam * ANG_STEP + th;
    const float rx = cosf(ang), ry = sinf(ang);

    float u = INFINITY;
    #pragma unroll
    for (int s = 0; s < SC; ++s) u = fminf(u, part[s * (NB * L_OBS) + t]);

    if (isinf(u)) {
        // No valid intersection: ref takes u_a[0] (argmin of all-inf picks idx 0).
        float4 s0 = seg[0];
        float sx = s0.z - s0.x, sy = s0.w - s0.y;
        float xd = x1 - s0.x,   yd = y1 - s0.y;
        float rxs   = sy * rx - sx * ry;
        float num_a = sx * yd - sy * xd;
        u = (fabsf(rxs) < EPS_PAR) ? 0.0f : (num_a / rxs);
    }

    float ix = x1 + rx * u;
    float iy = y1 + ry * u;
    float dx = ix - x1, dy = iy - y1;
    float c = cosf(th), s = sinf(th);
    out[t * 2 + 0] = ix;
    out[t * 2 + 1] = iy;
    const int off = NB * L_OBS * 2;
    out[off + t * 2 + 0] =  dx * c + dy * s;   // R = [[c,-s],[s,c]], out = d @ R
    out[off + t * 2 + 1] = -dx * s + dy * c;
}

// ---------------- fallback path (R2, LDS-staged) if ws too small ----------------
__global__ __launch_bounds__(256) void raycast_part_kernel(
    const float4* __restrict__ seg, const float* __restrict__ pose,
    float* __restrict__ ws) {
    __shared__ float4 s4[SEGS];
    __shared__ float  sna[SEGS];
    __shared__ float  s_red[4][64];
    const int gid = blockIdx.x;
    const int sc = gid & (SC - 1);
    const int bg = (gid >> 4) & 7;
    const int b  = gid >> 7;
    const float x1 = pose[b * 3 + 0];
    const float y1 = pose[b * 3 + 1];
    const float th = pose[b * 3 + 2];
    const int tid = threadIdx.x;
    for (int i = tid; i < SEGS; i += 256) {
        float4 v = seg[sc * SEGS + i];
        float sx = v.z - v.x, sy = v.w - v.y;
        float xd = x1 - v.x, yd = y1 - v.y;
        s4[i]  = make_float4(sx, sy, xd, yd);
        sna[i] = sx * yd - sy * xd;
    }
    const int lane = tid & 63;
    const int w    = tid >> 6;
    const int beam = bg * 64 + lane;
    const float ang = (float)beam * ANG_STEP + th;
    const float rx = cosf(ang), ry = sinf(ang);
    __syncthreads();
    float umin = INFINITY;
    const float4* p  = &s4[w * 128];
    const float*  pn = &sna[w * 128];
    #pragma unroll 8
    for (int i = 0; i < 128; ++i) {
        float4 s = p[i];
        float na = pn[i];
        float rxs = s.y * rx - s.x * ry;
        float nb  = rx * s.w - ry * s.z;
        float r   = __builtin_amdgcn_rcpf(rxs);
        float ua  = na * r;
        float ub  = nb * r;
        bool ok = (fabsf(rxs) >= EPS_PAR) & (ub >= 0.0f) & (ub <= 1.0f) & (ua >= 0.0f);
        umin = fminf(umin, ok ? ua : INFINITY);
    }
    s_red[w][lane] = umin;
    __syncthreads();
    if (w == 0) {
        float m = fminf(fminf(s_red[0][lane], s_red[1][lane]),
                        fminf(s_red[2][lane], s_red[3][lane]));
        ws[sc * (NB * L_OBS) + b * L_OBS + beam] = m;
    }
}

extern "C" void kernel_launch(void* const* d_in, const int* in_sizes, int n_in,
                              void* d_out, int out_size, void* d_ws, size_t ws_size,
                              hipStream_t stream) {
    const float4* seg  = (const float4*)d_in[0];   // (N,4) float32
    const float*  pose = (const float*)d_in[1];    // (B,3) float32
    float* out = (float*)d_out;

    if (ws_size >= (size_t)(RECS_FLOATS + PART_FLOATS) * sizeof(float)) {
        float* recs = (float*)d_ws;
        float* part = recs + RECS_FLOATS;
        prep_kernel<<<NB * NSEG / 256, 256, 0, stream>>>(seg, pose, recs);
        raycast_scalar_kernel<<<1024, 256, 0, stream>>>(recs, pose, part);
        finalize_part_kernel<<<16, 256, 0, stream>>>(seg, pose, part, out);
    } else if (ws_size >= (size_t)PART_FLOATS * sizeof(float)) {
        float* part = (float*)d_ws;
        raycast_part_kernel<<<1024, 256, 0, stream>>>(seg, pose, part);
        finalize_part_kernel<<<16, 256, 0, stream>>>(seg, pose, part, out);
    }
}

// Round 4
// 25.606 us; speedup vs baseline: 1.1861x; 1.1861x over previous
//
#include <hip/hip_runtime.h>
#include <math.h>

#define L_OBS   512
#define NSEG    8192
#define NB      8
#define EPS_PAR 1e-4f
#define ANG_STEP 0.012271846644580566f  // FOV / L_OBS
#define SC      16
#define SEGS    (NSEG / SC)             // 512 segments per chunk
#define PART_FLOATS  (SC * NB * L_OBS)

// Block = (b, beamgroup of 64, segchunk of 512). lane = beam; wave = 128-seg subchunk.
// Segment data read DIRECTLY from global (wave-uniform address -> one L1 line,
// broadcast). No LDS staging: R2's staged bytes were each read exactly once, and
// the ds_read pipe (17.8 cyc/iter x 16 waves/CU) was the bottleneck.
__global__ __launch_bounds__(256) void raycast_kernel(
    const float4* __restrict__ seg, const float* __restrict__ pose,
    float* __restrict__ part) {
    __shared__ float s_red[4][64];

    const int gid = blockIdx.x;
    const int sc = gid & (SC - 1);
    const int bg = (gid >> 4) & 7;
    const int b  = gid >> 7;

    const int tid  = threadIdx.x;
    const int lane = tid & 63;
    const int w    = tid >> 6;

    const float x1 = pose[b * 3 + 0];
    const float y1 = pose[b * 3 + 1];
    const float th = pose[b * 3 + 2];
    const int beam = bg * 64 + lane;
    const float ang = (float)beam * ANG_STEP + th;
    const float rx = cosf(ang);
    const float ry = sinf(ang);
    const float INF = __builtin_inff();

    const float4* __restrict__ p = seg + (sc << 9) + (w << 7);

    float umin = INF;
    #pragma unroll 8
    for (int i = 0; i < 128; ++i) {
        float4 v = p[i];                  // wave-uniform 16B load, L1 broadcast
        float sx = v.z - v.x;
        float sy = v.w - v.y;
        float xd = x1 - v.x;
        float yd = y1 - v.y;
        float rxs = sy * rx - sx * ry;
        float na  = sx * yd - sy * xd;
        float nb  = rx * yd - ry * xd;
        float r   = __builtin_amdgcn_rcpf(rxs);
        float ua  = na * r;
        float ub  = nb * r;
        bool ok = (fabsf(rxs) >= EPS_PAR) & (ub >= 0.0f) & (ub <= 1.0f) & (ua >= 0.0f);
        umin = fminf(umin, ok ? ua : INF);
    }

    s_red[w][lane] = umin;
    __syncthreads();
    if (w == 0) {
        float m = fminf(fminf(s_red[0][lane], s_red[1][lane]),
                        fminf(s_red[2][lane], s_red[3][lane]));
        part[sc * (NB * L_OBS) + b * L_OBS + beam] = m;
    }
}

__global__ void finalize_part_kernel(const float4* __restrict__ seg,
                                     const float* __restrict__ pose,
                                     const float* __restrict__ part,
                                     float* __restrict__ out) {
    int t = blockIdx.x * blockDim.x + threadIdx.x;
    if (t >= NB * L_OBS) return;
    const int b    = t >> 9;
    const int beam = t & (L_OBS - 1);
    const float x1 = pose[b * 3 + 0];
    const float y1 = pose[b * 3 + 1];
    const float th = pose[b * 3 + 2];
    const float ang = (float)beam * ANG_STEP + th;
    const float rx = cosf(ang), ry = sinf(ang);

    float u = INFINITY;
    #pragma unroll
    for (int s = 0; s < SC; ++s) u = fminf(u, part[s * (NB * L_OBS) + t]);

    if (isinf(u)) {
        // No valid intersection: ref takes u_a[0] (argmin of all-inf picks idx 0).
        float4 s0 = seg[0];
        float sx = s0.z - s0.x, sy = s0.w - s0.y;
        float xd = x1 - s0.x,   yd = y1 - s0.y;
        float rxs   = sy * rx - sx * ry;
        float num_a = sx * yd - sy * xd;
        u = (fabsf(rxs) < EPS_PAR) ? 0.0f : (num_a / rxs);
    }

    float ix = x1 + rx * u;
    float iy = y1 + ry * u;
    float dx = ix - x1, dy = iy - y1;
    float c = cosf(th), s = sinf(th);
    out[t * 2 + 0] = ix;
    out[t * 2 + 1] = iy;
    const int off = NB * L_OBS * 2;
    out[off + t * 2 + 0] =  dx * c + dy * s;   // R = [[c,-s],[s,c]], out = d @ R
    out[off + t * 2 + 1] = -dx * s + dy * c;
}

extern "C" void kernel_launch(void* const* d_in, const int* in_sizes, int n_in,
                              void* d_out, int out_size, void* d_ws, size_t ws_size,
                              hipStream_t stream) {
    const float4* seg  = (const float4*)d_in[0];   // (N,4) float32
    const float*  pose = (const float*)d_in[1];    // (B,3) float32
    float* out = (float*)d_out;
    float* part = (float*)d_ws;                    // [SC][NB*L_OBS] partial mins

    raycast_kernel<<<1024, 256, 0, stream>>>(seg, pose, part);
    finalize_part_kernel<<<16, 256, 0, stream>>>(seg, pose, part, out);
}